// Round 7
// baseline (354.934 us; speedup 1.0000x reference)
//
#include <hip/hip_runtime.h>
#include <hip/hip_bf16.h>
#include <stdint.h>

using short8 = __attribute__((ext_vector_type(8))) short;
using f32x4  = __attribute__((ext_vector_type(4))) float;

#define NBITS 3
#define NHEADS 8
#define BATCH 8192
#define DFEAT 512
#define DBASE 1024
#define DHH   1024
#define DOUT  512
#define XCOLS (NBITS + DFEAT)   // 515

static __device__ __forceinline__ unsigned short f2bf(float f) {
    union { float f; unsigned u; } v; v.f = f;
    unsigned r = v.u + 0x7FFFu + ((v.u >> 16) & 1u);   // RNE
    return (unsigned short)(r >> 16);
}

// ---------------- bucket rows by head ----------------
__global__ void k_bucket(const float* __restrict__ x, int* __restrict__ cnt,
                         int* __restrict__ rows) {
    int r = blockIdx.x * 256 + threadIdx.x;
    if (r >= BATCH) return;
    const float* xr = x + (size_t)r * XCOLS;
    int h = (xr[0] > 0.5f ? 1 : 0) | (xr[1] > 0.5f ? 2 : 0) | (xr[2] > 0.5f ? 4 : 0);
    int slot = atomicAdd(cnt + h, 1);
    rows[h * BATCH + slot] = r;
}

// ---------------- feat fp32 -> bf16 [8192][512] ----------------
__global__ void k_feat(const float* __restrict__ x, unsigned short* __restrict__ feat) {
    int t = blockIdx.x * 256 + threadIdx.x;
    int row = t >> 6, c8 = (t & 63) << 3;
    const float* src = x + (size_t)row * XCOLS + NBITS + c8;
    short8 v;
#pragma unroll
    for (int i = 0; i < 8; ++i) v[i] = (short)f2bf(src[i]);
    *(short8*)(feat + (size_t)row * DFEAT + c8) = v;
}

// ---------------- W[b][K][N] fp32 -> WT[b][N][K] bf16 ----------------
__global__ void k_transpose(const float* __restrict__ W, unsigned short* __restrict__ WT,
                            int K, int N) {
    __shared__ float tile[32][33];
    int b  = blockIdx.z;
    int n0 = blockIdx.x << 5, k0 = blockIdx.y << 5;
    int tx = threadIdx.x & 31, ty = threadIdx.x >> 5;
    const float* Wb = W + (size_t)b * K * N;
    unsigned short* WTb = WT + (size_t)b * K * N;
#pragma unroll
    for (int j = 0; j < 32; j += 8)
        tile[ty + j][tx] = Wb[(size_t)(k0 + ty + j) * N + n0 + tx];
    __syncthreads();
#pragma unroll
    for (int j = 0; j < 32; j += 8)
        WTb[(size_t)(n0 + ty + j) * K + k0 + tx] = f2bf(tile[tx][ty + j]);
}

// ========= 64xBN GEMM: A staged in 256-k LDS chunks (dbuf), B read DIRECT global->VGPR =========
// C[rows][n] = act(A[rows] @ BT[head]^T + bias[head]);  BT is [N][K] row-major.
// Block: 256 thr (4 waves, each owns a 64x(NF*16) col-band).  LDS 2x32KB -> 2 blocks/CU.
// One barrier per 256-k chunk (8 BK=32 steps) instead of per step: the next chunk's
// global_load_lds issues at chunk top and its latency hides under ~8 steps of MFMA.
// B-frags are plain vector loads inside a fully unrolled chunk body -> compiler pipelines
// them with counted vmcnt (no barriers interfere within the chunk).
// A-chunk LDS layout: [64 rows][32 chunks of 16B], chunk XOR-swizzled by (row&7)
// (inverse swizzle pre-applied to the global source; linear DMA dest; swizzled ds_read).
template<bool GATHER, bool RELU, bool OUTBF16, int NF>
__global__ __launch_bounds__(256, 2)
void k_gemmd(const unsigned short* __restrict__ A, int lda, int K,
             const unsigned short* __restrict__ BT,
             const float* __restrict__ bias,
             void* __restrict__ C, int ldc,
             const int* __restrict__ rowsAll, const int* __restrict__ cntAll,
             int Nfull, int nshift) {
    constexpr int BN = NF * 16 * 4;      // 4 waves * NF frags * 16
    const int bid  = blockIdx.x;
    const int mt   = bid & 127;
    const int nt   = (bid >> 7) & ((1 << nshift) - 1);
    const int head = GATHER ? (bid >> (7 + nshift)) : 0;
    const int m0 = mt * 64;
    const int n0 = nt * BN;
    int M = BATCH;
    const int* rows = nullptr;
    if (GATHER) {
        M = cntAll[head];
        if (m0 >= M) return;             // uniform early exit before any barrier
        rows = rowsAll + head * BATCH;
    }
    const unsigned short* BTh = BT + (size_t)head * Nfull * K;
    const float* biash = bias + (size_t)head * Nfull;

    __shared__ __align__(16) char lds[2 * 32768];

    const int t    = threadIdx.x;
    const int w    = t >> 6;
    const int lane = t & 63;
    const int ln = lane & 15, lq = lane >> 4;
    const int r7 = ln & 7;

    // ---- A staging source pointers: i=0..7; linear dest chunk c=i*256+t;
    //      row r=c>>5, phys=c&31, logical=phys^(r&7) ----
    const unsigned short* gsrc[8];
#pragma unroll
    for (int i = 0; i < 8; ++i) {
        int r  = i * 8 + (t >> 5);
        int lg = (t & 31) ^ (r & 7);
        int gr;
        if (GATHER) { int idx = m0 + r; idx = idx < M ? idx : M - 1; gr = rows[idx]; }
        else gr = m0 + r;
        gsrc[i] = A + (size_t)gr * lda + lg * 8;
    }
    // ---- B direct-load pointers (one per n-frag) ----
    const unsigned short* gb[NF];
#pragma unroll
    for (int n = 0; n < NF; ++n) {
        int col = n0 + w * (NF * 16) + n * 16 + ln;
        gb[n] = BTh + (size_t)col * K + lq * 8;
    }
    const int dstw = w * 1024;           // wave-uniform LDS base; HW adds lane*16

#define STAGEQ(cq_, d_)                                                                    \
    { _Pragma("unroll") for (int i = 0; i < 8; ++i)                                        \
        __builtin_amdgcn_global_load_lds(                                                  \
            (const __attribute__((address_space(1))) void*)(gsrc[i] + (cq_) * 256),        \
            (__attribute__((address_space(3))) void*)(lds + (d_) * 32768 + i * 4096 + dstw), \
            16, 0, 0); }

    f32x4 acc[4][NF] = {};
    const int NC = K >> 8;               // number of 256-k chunks

    STAGEQ(0, 0);
    __syncthreads();                     // chunk 0 resident

    for (int cq = 0; cq < NC; ++cq) {
        const int d = cq & 1;
        if (cq + 1 < NC) STAGEQ(cq + 1, d ^ 1);      // prefetch next chunk (drains at chunk-end barrier)
        const char* cA = lds + d * 32768;
        const unsigned short* bq[NF];
#pragma unroll
        for (int n = 0; n < NF; ++n) bq[n] = gb[n] + cq * 256;
#pragma unroll
        for (int ks = 0; ks < 8; ++ks) {             // 8 BK=32 steps, no barriers inside
            short8 af[4], bf[NF];
#pragma unroll
            for (int m = 0; m < 4; ++m) {
                int row  = m * 16 + ln;
                int phys = ((ks * 4) | lq) ^ r7;
                af[m] = *(const short8*)(cA + row * 512 + phys * 16);
            }
#pragma unroll
            for (int n = 0; n < NF; ++n)
                bf[n] = *(const short8*)(bq[n] + ks * 32);
#pragma unroll
            for (int m = 0; m < 4; ++m)
#pragma unroll
                for (int n = 0; n < NF; ++n)
                    acc[m][n] = __builtin_amdgcn_mfma_f32_16x16x32_bf16(af[m], bf[n], acc[m][n], 0, 0, 0);
        }
        __syncthreads();                 // next chunk ready; old buffer reusable
    }
#undef STAGEQ

    // epilogue: C/D layout col = lane&15, row = (lane>>4)*4 + j  (64-row tile)
#pragma unroll
    for (int n = 0; n < NF; ++n) {
        int col = n0 + w * (NF * 16) + n * 16 + ln;
        float bv = biash[col];
#pragma unroll
        for (int m = 0; m < 4; ++m) {
#pragma unroll
            for (int j = 0; j < 4; ++j) {
                int rt = m * 16 + lq * 4 + j;
                int grow;
                if (GATHER) {
                    if (m0 + rt >= M) continue;
                    grow = rows[m0 + rt];
                } else {
                    grow = m0 + rt;
                }
                float v = acc[m][n][j] + bv;
                if (RELU) v = fmaxf(v, 0.0f);
                if (OUTBF16)
                    ((unsigned short*)C)[(size_t)grow * ldc + col] = f2bf(v);
                else
                    ((float*)C)[(size_t)grow * ldc + col] = v;
            }
        }
    }
}

extern "C" void kernel_launch(void* const* d_in, const int* in_sizes, int n_in,
                              void* d_out, int out_size, void* d_ws, size_t ws_size,
                              hipStream_t stream) {
    const float* x   = (const float*)d_in[0];
    const float* Wb  = (const float*)d_in[1];
    const float* bb  = (const float*)d_in[2];
    const float* Wh1 = (const float*)d_in[3];
    const float* bh1 = (const float*)d_in[4];
    const float* Wh2 = (const float*)d_in[5];
    const float* bh2 = (const float*)d_in[6];

    char* ws = (char*)d_ws;
    unsigned short* feat = (unsigned short*)(ws);                          //  8 MB
    unsigned short* WbT  = (unsigned short*)(ws + (8ull  << 20));          //  1 MB
    unsigned short* Wh1T = (unsigned short*)(ws + (9ull  << 20));          // 16 MB
    unsigned short* Wh2T = (unsigned short*)(ws + (25ull << 20));          //  8 MB
    unsigned short* base = (unsigned short*)(ws + (33ull << 20));          // 16 MB
    unsigned short* hbuf = (unsigned short*)(ws + (49ull << 20));          // 16 MB
    int* rows            = (int*)(ws + (65ull << 20));                     // 256 KB
    int* cnt             = (int*)(ws + (65ull << 20) + (256ull << 10));    // 32 B

    hipMemsetAsync(cnt, 0, NHEADS * sizeof(int), stream);
    k_bucket<<<BATCH / 256, 256, 0, stream>>>(x, cnt, rows);
    k_feat<<<(BATCH * 64) / 256, 256, 0, stream>>>(x, feat);
    k_transpose<<<dim3(DBASE / 32, DFEAT / 32, 1), 256, 0, stream>>>(Wb, WbT, DFEAT, DBASE);
    k_transpose<<<dim3(DHH / 32, DBASE / 32, NHEADS), 256, 0, stream>>>(Wh1, Wh1T, DBASE, DHH);
    k_transpose<<<dim3(DOUT / 32, DHH / 32, NHEADS), 256, 0, stream>>>(Wh2, Wh2T, DHH, DOUT);

    // GEMM1: base = relu(feat @ Wb + bb)   M=8192 K=512 N=1024 ; 128 mt x 4 nt (BN=256)
    k_gemmd<false, true, true, 4><<<512, 256, 0, stream>>>(
        feat, DFEAT, DFEAT, WbT, bb, base, DBASE, nullptr, nullptr, DBASE, 2);
    // GEMM2: h = relu(base @ Wh1[h] + bh1[h])  grouped, K=1024 N=1024 ; 128 mt x 4 nt x 8 heads
    k_gemmd<true, true, true, 4><<<4096, 256, 0, stream>>>(
        base, DBASE, DBASE, Wh1T, bh1, hbuf, DHH, rows, cnt, DHH, 2);
    // GEMM3: out = h @ Wh2[h] + bh2[h]  grouped, K=1024 N=512, fp32 out ; BN=128: 128 mt x 4 nt x 8
    k_gemmd<true, false, false, 2><<<4096, 256, 0, stream>>>(
        hbuf, DHH, DHH, Wh2T, bh2, d_out, DOUT, rows, cnt, DOUT, 2);
}